// Round 1
// baseline (469.979 us; speedup 1.0000x reference)
//
#include <hip/hip_runtime.h>
#include <hip/hip_bf16.h>

// Problem constants
#define B_  32
#define T_  1500
#define E_  512
#define A_  512
#define C_  10
#define KH  100      // conv half-width
#define KW  201      // conv width
#define O_  512
#define M_  (B_*T_)  // 48000 rows
#define KP  544      // K' = 512 (enc) + 32 (conv padded)
#define SCALING_ 2.0f

typedef __bf16 bf16;
typedef __attribute__((ext_vector_type(8))) __bf16 bf16x8;
typedef __attribute__((ext_vector_type(4))) float f32x4;

// ---------------- prep: bias[b][a] = b_enc[a] + dec_z[b,:] @ W_dec[:,a] ----------------
__global__ void prep_bias(const float* __restrict__ dec_z, const float* __restrict__ W_dec,
                          const float* __restrict__ b_enc, float* __restrict__ bias) {
    int idx = blockIdx.x * 256 + threadIdx.x;   // [0, 16384)
    int b = idx >> 9, a = idx & 511;
    float acc = b_enc[a];
#pragma unroll 4
    for (int d = 0; d < 512; ++d)
        acc += dec_z[b * 512 + d] * W_dec[d * 512 + a];
    bias[idx] = acc;
}

// ---------------- prep: wt[a][k] bf16, k<512: W_enc[k][a]; 512<=k<522: W_att[k-512][a]; else 0
__global__ void prep_wt(const float* __restrict__ W_enc, const float* __restrict__ W_att,
                        bf16* __restrict__ wt) {
    int k = blockIdx.x;            // [0, 544)
    for (int a = threadIdx.x; a < 512; a += 256) {
        float v;
        if (k < 512)       v = W_enc[k * 512 + a];
        else if (k < 522)  v = W_att[(k - 512) * 512 + a];
        else               v = 0.0f;
        wt[a * KP + k] = (bf16)v;
    }
}

// ---------------- prep: convpad[row][0..9] = conv(att_prev)[b, c, t] @ identity, rest 0 -----
__global__ void prep_conv(const float* __restrict__ att_prev, const float* __restrict__ conv_w,
                          bf16* __restrict__ convpad) {
    int tc = blockIdx.x;   // 6 chunks of 256 t's
    int b  = blockIdx.y;   // 32
    int tid = threadIdx.x;
    __shared__ float s_att[456];
    __shared__ float s_w[C_ * KW];   // 2010
    int t0 = tc * 256;
    for (int i = tid; i < 456; i += 256) {
        int ti = t0 - KH + i;
        s_att[i] = (ti >= 0 && ti < T_) ? att_prev[b * T_ + ti] : 0.0f;
    }
    for (int i = tid; i < C_ * KW; i += 256) s_w[i] = conv_w[i];
    __syncthreads();
    int t = t0 + tid;
    if (t < T_) {
        float acc[C_];
#pragma unroll
        for (int c = 0; c < C_; ++c) acc[c] = 0.0f;
        for (int j = 0; j < KW; ++j) {
            float a = s_att[tid + j];
#pragma unroll
            for (int c = 0; c < C_; ++c) acc[c] += a * s_w[c * KW + j];
        }
        bf16* dst = convpad + (size_t)(b * T_ + t) * 32;
#pragma unroll
        for (int c = 0; c < C_; ++c) dst[c] = (bf16)acc[c];
#pragma unroll
        for (int c = C_; c < 32; ++c) dst[c] = (bf16)0.0f;
    }
}

// ---------------- main fused GEMM: e[row] = gvec . tanh(enc@W_enc + conv@W_att + bias) -----
// block = 256 thr (4 waves), 64 rows/block, N=512 (32 n-tiles), K'=544 (17 k-steps)
__global__ __launch_bounds__(256) void main_gemm(
        const float* __restrict__ enc, const bf16* __restrict__ convpad,
        const bf16* __restrict__ wt, const float* __restrict__ bias,
        const float* __restrict__ gvec, float* __restrict__ e_out) {
    __shared__ bf16 a_lds[4 * 16 * 512];   // 64 KB, XOR-swizzled
    const int tid  = threadIdx.x;
    const int lane = tid & 63;
    const int wid  = tid >> 6;
    const int m0w  = blockIdx.x * 64 + wid * 16;   // wave's first global row

    // --- stage this wave's 16 rows x 512 (enc, f32->bf16) into LDS ---
    {
        char* base = (char*)a_lds + wid * 16384;
#pragma unroll
        for (int i = 0; i < 16; ++i) {
            const float* p = enc + (size_t)(m0w + i) * 512 + lane * 8;
            float4 f0 = *(const float4*)(p);
            float4 f1 = *(const float4*)(p + 4);
            bf16x8 v;
            v[0] = (bf16)f0.x; v[1] = (bf16)f0.y; v[2] = (bf16)f0.z; v[3] = (bf16)f0.w;
            v[4] = (bf16)f1.x; v[5] = (bf16)f1.y; v[6] = (bf16)f1.z; v[7] = (bf16)f1.w;
            int off = i * 1024 + ((lane * 16) ^ ((i & 7) << 4));
            *(bf16x8*)(base + off) = v;
        }
    }
    __syncthreads();

    const int g    = lane >> 4;       // 0..3 (k-group)
    const int c15  = lane & 15;       // A-row / B-col within tile
    const int Cx   = (c15 & 7) << 4;  // XOR constant for a-reads
    const char* abase = (char*)a_lds + wid * 16384 + c15 * 1024;
    const int g16  = g * 16;

    // D rows for this lane: m0w + g*4 + r
    int brw[4];
#pragma unroll
    for (int r = 0; r < 4; ++r) brw[r] = ((m0w + g * 4 + r) / T_) * 512;

    // conv A-fragment (k-step 16): same for all nt — hoist
    bf16x8 a_cv = *(const bf16x8*)(convpad + (size_t)(m0w + c15) * 32 + g * 8);
    const bf16* bcol0 = wt + (size_t)c15 * KP + g * 8;

    float s[4] = {0.f, 0.f, 0.f, 0.f};
    for (int nt = 0; nt < 32; ++nt) {
        f32x4 acc = {0.f, 0.f, 0.f, 0.f};
        const bf16* bp = bcol0 + nt * 16 * KP;
#pragma unroll
        for (int kt = 0; kt < 16; ++kt) {
            bf16x8 av = *(const bf16x8*)(abase + ((kt * 64 + g16) ^ Cx));
            bf16x8 bv = *(const bf16x8*)(bp + kt * 32);
            acc = __builtin_amdgcn_mfma_f32_16x16x32_bf16(av, bv, acc, 0, 0, 0);
        }
        {   // conv k-step (k = 512..543)
            bf16x8 bv = *(const bf16x8*)(bp + 512);
            acc = __builtin_amdgcn_mfma_f32_16x16x32_bf16(a_cv, bv, acc, 0, 0, 0);
        }
        int n = nt * 16 + c15;
        float gv = gvec[n];
#pragma unroll
        for (int r = 0; r < 4; ++r) {
            float x  = acc[r] + bias[brw[r] + n];
            float ex = __expf(2.0f * x);                      // exp(2x)
            float th = 1.0f - __fdividef(2.0f, ex + 1.0f);    // tanh(x)
            s[r] += gv * th;
        }
    }
    // reduce over the 16 lanes sharing the same rows (same g)
#pragma unroll
    for (int m = 1; m < 16; m <<= 1) {
#pragma unroll
        for (int r = 0; r < 4; ++r) s[r] += __shfl_xor(s[r], m, 64);
    }
    if (c15 == 0) {
#pragma unroll
        for (int r = 0; r < 4; ++r) e_out[m0w + g * 4 + r] = s[r];
    }
}

// ---------------- softmax over T per batch: w = softmax(SCALING * e) ----------------
__global__ void softmax_k(const float* __restrict__ e_in, float* __restrict__ w_out) {
    int b = blockIdx.x, tid = threadIdx.x;
    __shared__ float red[256];
    float v[6];
    float mx = -1e30f;
#pragma unroll
    for (int i = 0; i < 6; ++i) {
        int t = i * 256 + tid;
        v[i] = (t < T_) ? SCALING_ * e_in[b * T_ + t] : -1e30f;
        mx = fmaxf(mx, v[i]);
    }
    red[tid] = mx; __syncthreads();
    for (int st = 128; st > 0; st >>= 1) {
        if (tid < st) red[tid] = fmaxf(red[tid], red[tid + st]);
        __syncthreads();
    }
    mx = red[0]; __syncthreads();
    float sum = 0.f;
#pragma unroll
    for (int i = 0; i < 6; ++i) { v[i] = __expf(v[i] - mx); sum += v[i]; }
    red[tid] = sum; __syncthreads();
    for (int st = 128; st > 0; st >>= 1) {
        if (tid < st) red[tid] += red[tid + st];
        __syncthreads();
    }
    float inv = 1.0f / red[0];
#pragma unroll
    for (int i = 0; i < 6; ++i) {
        int t = i * 256 + tid;
        if (t < T_) w_out[b * T_ + t] = v[i] * inv;
    }
}

// ---------------- context partial: partial[ty][b][e] = sum_{t in chunk} w[b,t] enc[b,t,e] --
__global__ void ctx_partial(const float* __restrict__ enc, const float* __restrict__ w,
                            float* __restrict__ partial) {
    int e  = blockIdx.x * 256 + threadIdx.x;   // gridDim.x = 2
    int ty = blockIdx.y;                        // 8
    int b  = blockIdx.z;                        // 32
    int t0 = ty * 188;
    int t1 = min(t0 + 188, T_);
    float acc = 0.f;
#pragma unroll 4
    for (int t = t0; t < t1; ++t)
        acc += w[b * T_ + t] * enc[((size_t)b * T_ + t) * 512 + e];
    partial[(ty * 32 + b) * 512 + e] = acc;
}

// ---------------- output proj: c[b] = (sum partials) @ W_o + b_o ----------------
__global__ void out_proj(const float* __restrict__ partial, const float* __restrict__ Wo,
                         const float* __restrict__ bo, float* __restrict__ out) {
    int b = blockIdx.x, tid = threadIdx.x;
    __shared__ float ctx[512];
    for (int e = tid; e < 512; e += 256) {
        float s = 0.f;
#pragma unroll
        for (int p = 0; p < 8; ++p) s += partial[(p * 32 + b) * 512 + e];
        ctx[e] = s;
    }
    __syncthreads();
    for (int o = tid; o < 512; o += 256) {
        float acc = bo[o];
#pragma unroll 4
        for (int e = 0; e < 512; ++e) acc += ctx[e] * Wo[e * 512 + o];
        out[b * 512 + o] = acc;
    }
}

extern "C" void kernel_launch(void* const* d_in, const int* in_sizes, int n_in,
                              void* d_out, int out_size, void* d_ws, size_t ws_size,
                              hipStream_t stream) {
    const float* enc      = (const float*)d_in[0];
    // d_in[1] = enc_len (unused: all rows are full length T)
    const float* dec_z    = (const float*)d_in[2];
    const float* att_prev = (const float*)d_in[3];
    const float* W_enc    = (const float*)d_in[4];
    const float* b_enc    = (const float*)d_in[5];
    const float* W_dec    = (const float*)d_in[6];
    const float* W_att    = (const float*)d_in[7];
    const float* conv_w   = (const float*)d_in[8];
    const float* gvec     = (const float*)d_in[9];
    const float* W_o      = (const float*)d_in[10];
    const float* b_o      = (const float*)d_in[11];

    // workspace layout (bytes):
    //   [0, 65536)           bias        f32 [32][512]
    //   [65536, 257536)      e_out       f32 [48000]
    //   [257536, 781824)     partial     f32 [8][32][512]
    //   [781824, 3853824)    convpad     bf16 [48000][32]
    //   [3853824, 4410880)   wt          bf16 [512][544]
    char* ws = (char*)d_ws;
    float* bias    = (float*)(ws);
    float* e_buf   = (float*)(ws + 65536);
    float* partial = (float*)(ws + 257536);
    bf16*  convpad = (bf16*)(ws + 781824);
    bf16*  wt      = (bf16*)(ws + 3853824);

    float* c_out = (float*)d_out;           // [32][512]
    float* w_out = c_out + B_ * O_;         // [32][1500]

    prep_bias<<<64, 256, 0, stream>>>(dec_z, W_dec, b_enc, bias);
    prep_wt<<<KP, 256, 0, stream>>>(W_enc, W_att, wt);
    prep_conv<<<dim3(6, B_), 256, 0, stream>>>(att_prev, conv_w, convpad);
    main_gemm<<<M_ / 64, 256, 0, stream>>>(enc, convpad, wt, bias, gvec, e_buf);
    softmax_k<<<B_, 256, 0, stream>>>(e_buf, w_out);
    ctx_partial<<<dim3(2, 8, B_), 256, 0, stream>>>(enc, w_out, partial);
    out_proj<<<B_, 256, 0, stream>>>(partial, W_o, b_o, c_out);
}